// Round 2
// baseline (163.181 us; speedup 1.0000x reference)
//
#include <hip/hip_runtime.h>
#include <math.h>

#define NB 8
#define NC 64
#define NN 4096
#define SHIFTC 20.0f    // fixed softmax shift (shift-invariant; scores max ~11)

typedef __attribute__((ext_vector_type(8))) short short8;
typedef __attribute__((ext_vector_type(4))) float float4v;
typedef __attribute__((ext_vector_type(4))) unsigned int uint4v;
typedef __attribute__((ext_vector_type(2))) int int2v;

__device__ inline unsigned short f2bf(float f) {        // RNE
    unsigned int u = __builtin_bit_cast(unsigned int, f);
    unsigned int r = (u + 0x7FFFu + ((u >> 16) & 1u)) >> 16;
    return (unsigned short)r;
}
// round-half-up bf16 of lo,hi packed into one dword (2 v_add + 1 v_perm)
__device__ inline unsigned int bfpack(float lo, float hi) {
    unsigned int a = __builtin_bit_cast(unsigned int, lo) + 0x8000u;
    unsigned int b = __builtin_bit_cast(unsigned int, hi) + 0x8000u;
    return __builtin_amdgcn_perm(b, a, 0x07060302u);
}
// single-instruction RNE pack: D[15:0]=bf16(lo), D[31:16]=bf16(hi)
// (proven pattern: guide T12 / learn_hip m214v22 — asm cvt_pk feeding the
// permlane32_swap BUILTIN so the compiler inserts the permlane wait-state)
__device__ inline unsigned int cvtpk(float lo, float hi) {
    unsigned int r;
    asm("v_cvt_pk_bf16_f32 %0, %1, %2" : "=v"(r) : "v"(lo), "v"(hi));
    return r;
}
// x' = [x_lo | y_lo], y' = [x_hi | y_hi]  (exchanges x's high 32 lanes with
// y's low 32).  Builtin, NOT raw asm: gfx950 permlane*_swap has a documented
// VALU-write->read wait-state the compiler must insert.
__device__ inline void plswap(unsigned int& x, unsigned int& y) {
    int2v r = __builtin_amdgcn_permlane32_swap((int)x, (int)y, false, false);
    x = (unsigned int)r[0];
    y = (unsigned int)r[1];
}

// ---------------------------------------------------------------------------
// Kernel 1: MFMA projections.  C[80ch x N] = W[80x64] * x[64xN] + bias.
// Block = 4 waves x 16 px = 64 px; grid (NN/64, NB) = 512 blocks.
// V is stored with bits 2<->3 of the pixel index (within 16-groups) swapped,
// so attn's PV A-fragment needs only permlane32 swaps (the residual k-slot
// permutation is absorbed here; PV's contraction is invariant to a common
// permutation of P's and V's k slots).
// ---------------------------------------------------------------------------
__global__ __launch_bounds__(256) void proj_mfma_kernel(
    const float* __restrict__ x,
    const float* __restrict__ wq, const float* __restrict__ bq,
    const float* __restrict__ wk, const float* __restrict__ bk,
    const float* __restrict__ wv, const float* __restrict__ bv,
    unsigned short* __restrict__ qo8, unsigned short* __restrict__ ko8,
    unsigned short* __restrict__ vo)
{
    const int b = blockIdx.y;
    const int wave = threadIdx.x >> 6, lane = threadIdx.x & 63;
    const int c0 = lane & 15, quad = lane >> 4;
    const int n0 = blockIdx.x * 64 + wave * 16;

    __shared__ unsigned short qkb[4][16][24];   // [wave][px][ch], 48B rows

    // x fragment: B[k=c][n=px], c = kc*32 + quad*8 + e, px = n0 + c0
    const float* xb = x + (size_t)b * NC * NN + n0 + c0;
    short8 xf[2];
#pragma unroll
    for (int kc = 0; kc < 2; ++kc)
#pragma unroll
        for (int e = 0; e < 8; ++e)
            xf[kc][e] = (short)f2bf(xb[(size_t)(kc * 32 + quad * 8 + e) * NN]);

    // j-permutation for V store: swap bits 2,3 of pixel-low-nibble
    const int c0p = (c0 & 3) | ((c0 & 8) >> 1) | ((c0 & 4) << 1);

    // ---- v tiles: ch = mt*16 + quad*4 + reg ----
#pragma unroll
    for (int mt = 0; mt < 4; ++mt) {
        short8 wf0, wf1;
#pragma unroll
        for (int e = 0; e < 8; ++e) {
            wf0[e] = (short)f2bf(wv[(mt * 16 + c0) * 64 + quad * 8 + e]);
            wf1[e] = (short)f2bf(wv[(mt * 16 + c0) * 64 + 32 + quad * 8 + e]);
        }
        float4v acc = {0.f, 0.f, 0.f, 0.f};
        acc = __builtin_amdgcn_mfma_f32_16x16x32_bf16(wf0, xf[0], acc, 0, 0, 0);
        acc = __builtin_amdgcn_mfma_f32_16x16x32_bf16(wf1, xf[1], acc, 0, 0, 0);
#pragma unroll
        for (int reg = 0; reg < 4; ++reg) {
            int ch = mt * 16 + quad * 4 + reg;
            vo[((size_t)b * NC + ch) * NN + n0 + c0p] = f2bf(acc[reg] + bv[ch]);
        }
    }

    // ---- qk tile: rows 0..7 = q, 8..15 = k ----
    {
        const float* wrow = (c0 < 8) ? (wq + c0 * 64) : (wk + (c0 - 8) * 64);
        short8 wf0, wf1;
#pragma unroll
        for (int e = 0; e < 8; ++e) {
            wf0[e] = (short)f2bf(wrow[quad * 8 + e]);
            wf1[e] = (short)f2bf(wrow[32 + quad * 8 + e]);
        }
        float4v acc = {0.f, 0.f, 0.f, 0.f};
        acc = __builtin_amdgcn_mfma_f32_16x16x32_bf16(wf0, xf[0], acc, 0, 0, 0);
        acc = __builtin_amdgcn_mfma_f32_16x16x32_bf16(wf1, xf[1], acc, 0, 0, 0);
        float a[4];
#pragma unroll
        for (int reg = 0; reg < 4; ++reg) {
            int qr = quad * 4 + reg;
            float bias = (qr < 8) ? bq[qr] : bk[qr - 8];
            a[reg] = acc[reg] + bias;
        }
        // lane holds C[ch'=quad*4+reg][px=c0] -> qkb[px][ch']
        *(uint2*)&qkb[wave][c0][quad * 4] = make_uint2(bfpack(a[0], a[1]), bfpack(a[2], a[3]));
        // same-wave LDS roundtrip (compiler inserts lgkmcnt)
        if (quad == 0) {
            uint4 qrow = *(const uint4*)&qkb[wave][c0][0];
            uint4 krow = *(const uint4*)&qkb[wave][c0][8];
            *(uint4*)&qo8[((size_t)b * NN + n0 + c0) * 8] = qrow;
            *(uint4*)&ko8[((size_t)b * NN + n0 + c0) * 8] = krow;
        }
    }
}

// ---------------------------------------------------------------------------
// Kernel 2: fused flash attention, j split across waves.
// P never touches LDS: the S^T -> A-frag transpose is 4 permlane32_swaps per
// qh (register-bit <-> lane-bit-q1 transpose); the residual (j bits 2<->3)
// permutation is baked into V's layout by kernel 1.  QK MFMA is seeded with
// C = -SHIFTC so softmax is a bare __expf.  Partial-O combine is one shared
// f32 accumulator via LDS atomicAdd, so LDS drops 33.8KB -> 8.9KB and there
// are no barriers in the main loop.
// ---------------------------------------------------------------------------
__global__ __launch_bounds__(256, 4) void attn_fused_kernel(
    const unsigned short* __restrict__ qo8, const unsigned short* __restrict__ ko8,
    const unsigned short* __restrict__ vo,
    const float* __restrict__ x, const float* __restrict__ gamma,
    float* __restrict__ out)
{
    const int b = blockIdx.y;
    const int i0b = blockIdx.x * 32;
    const int wave = threadIdx.x >> 6, lane = threadIdx.x & 63;
    const int c0 = lane & 15, quad = lane >> 4;

    __shared__ __align__(16) float oacc[32][65];   // single cross-wave O accumulator
    __shared__ float lbuf[4][2][16];

    // zero O accumulator before any ds_add (barrier guards wave skew)
    for (int i = threadIdx.x; i < 32 * 65; i += 256)
        ((float*)oacc)[i] = 0.f;
    __syncthreads();

    const int jbase = wave * (NN / 4);

    // Q fragments (B-operand): n=c0 -> query, k=quad*8+e (only k<8 real)
    short8 qf[2] = {};
    if (quad == 0) {
        qf[0] = *(const short8*)(qo8 + ((size_t)b * NN + i0b + c0) * 8);
        qf[1] = *(const short8*)(qo8 + ((size_t)b * NN + i0b + 16 + c0) * 8);
    }

    float4v acc[2][4];
#pragma unroll
    for (int qh = 0; qh < 2; ++qh)
#pragma unroll
        for (int ct = 0; ct < 4; ++ct) acc[qh][ct] = (float4v){0.f, 0.f, 0.f, 0.f};
    float lsum[2] = {0.f, 0.f};

    const unsigned short* vbase = vo + ((size_t)b * NC + c0) * NN + jbase + quad * 8;
    const unsigned short* kbase = ko8 + ((size_t)(b * NN + jbase + c0)) * 8;

    for (int t = 0; t < NN / 4 / 64; ++t) {
        const int jt = t * 64;
        short8 kf[4] = {};
        if (quad == 0) {
#pragma unroll
            for (int st = 0; st < 4; ++st)
                kf[st] = *(const short8*)(kbase + (size_t)(jt + st * 16) * 8);
        }
        short8 vf[4][2];
#pragma unroll
        for (int ct = 0; ct < 4; ++ct)
#pragma unroll
            for (int kc = 0; kc < 2; ++kc)
                vf[ct][kc] = *(const short8*)(vbase + (size_t)ct * 16 * NN + jt + kc * 32);

#pragma unroll
        for (int qh = 0; qh < 2; ++qh) {
            // S^T[64j x 16q] - SHIFTC (seeded in C): lane -> q=c0,
            // j = jbase + jt + st*16 + quad*4 + reg
            const float4v mC = {-SHIFTC, -SHIFTC, -SHIFTC, -SHIFTC};
            float4v s[4];
#pragma unroll
            for (int st = 0; st < 4; ++st)
                s[st] = __builtin_amdgcn_mfma_f32_16x16x32_bf16(kf[st], qf[qh], mC, 0, 0, 0);

            // p = exp(s) (compiler-visible: MFMA->VALU hazards handled),
            // lsum, pack to bf16 j-pair dwords D[st][w]
            unsigned int D[4][2];
            float ls = 0.f;
#pragma unroll
            for (int st = 0; st < 4; ++st) {
                float p0 = __expf(s[st][0]);
                float p1 = __expf(s[st][1]);
                float p2 = __expf(s[st][2]);
                float p3 = __expf(s[st][3]);
                ls += (p0 + p1) + (p2 + p3);
                D[st][0] = cvtpk(p0, p1);
                D[st][1] = cvtpk(p2, p3);
            }
            lsum[qh] += ls;

            // In-register transpose to PV A-frag layout (j bit2<->3 residual is
            // baked into V storage).  After swap(X,Y): X'=[X_lo|Y_lo], Y'=[X_hi|Y_hi].
            unsigned int a00 = D[0][0], b00 = D[1][0];  plswap(a00, b00);
            unsigned int a01 = D[0][1], b01 = D[1][1];  plswap(a01, b01);
            unsigned int a10 = D[2][0], b10 = D[3][0];  plswap(a10, b10);
            unsigned int a11 = D[2][1], b11 = D[3][1];  plswap(a11, b11);
            uint4v u0 = {a00, a01, b00, b01};   // kc=0: dwords m=0..3
            uint4v u1 = {a10, a11, b10, b11};   // kc=1
            short8 pf0 = __builtin_bit_cast(short8, u0);
            short8 pf1 = __builtin_bit_cast(short8, u1);

#pragma unroll
            for (int ct = 0; ct < 4; ++ct)
                acc[qh][ct] = __builtin_amdgcn_mfma_f32_16x16x32_bf16(
                    pf0, vf[ct][0], acc[qh][ct], 0, 0, 0);
#pragma unroll
            for (int ct = 0; ct < 4; ++ct)
                acc[qh][ct] = __builtin_amdgcn_mfma_f32_16x16x32_bf16(
                    pf1, vf[ct][1], acc[qh][ct], 0, 0, 0);
        }
    }

    // l partial for q = c0 (sum over quads)
#pragma unroll
    for (int qh = 0; qh < 2; ++qh) {
        lsum[qh] += __shfl_xor(lsum[qh], 16);
        lsum[qh] += __shfl_xor(lsum[qh], 32);
    }
    if (quad == 0) {
        lbuf[wave][0][c0] = lsum[0];
        lbuf[wave][1][c0] = lsum[1];
    }

    // cross-wave O combine: ds_add into the single accumulator
#pragma unroll
    for (int qh = 0; qh < 2; ++qh)
#pragma unroll
        for (int ct = 0; ct < 4; ++ct)
#pragma unroll
            for (int reg = 0; reg < 4; ++reg)
                atomicAdd(&oacc[qh * 16 + quad * 4 + reg][ct * 16 + c0], acc[qh][ct][reg]);
    __syncthreads();

    // cooperative epilogue: thread -> (q = tid&31, ch group = tid>>5)
    const int q = threadIdx.x & 31;
    const int cg = threadIdx.x >> 5;
    const float L = lbuf[0][q >> 4][q & 15] + lbuf[1][q >> 4][q & 15] +
                    lbuf[2][q >> 4][q & 15] + lbuf[3][q >> 4][q & 15];
    const float scale = gamma[0] / L;
    const size_t base = (size_t)b * NC * NN + i0b + q;
#pragma unroll
    for (int cc = 0; cc < 8; ++cc) {
        const int ch = cg * 8 + cc;
        const float O = oacc[q][ch];
        const size_t idx = base + (size_t)ch * NN;
        out[idx] = x[idx] + scale * O;
    }
}

// ---------------------------------------------------------------------------
extern "C" void kernel_launch(void* const* d_in, const int* in_sizes, int n_in,
                              void* d_out, int out_size, void* d_ws, size_t ws_size,
                              hipStream_t stream) {
    const float* x     = (const float*)d_in[0];
    const float* wq    = (const float*)d_in[1];
    const float* bq    = (const float*)d_in[2];
    const float* wk    = (const float*)d_in[3];
    const float* bk    = (const float*)d_in[4];
    const float* wv    = (const float*)d_in[5];
    const float* bv    = (const float*)d_in[6];
    const float* gamma = (const float*)d_in[7];
    float* out = (float*)d_out;

    unsigned short* wss = (unsigned short*)d_ws;
    unsigned short* qo8 = wss;                          // NB*NN*8 bf16
    unsigned short* ko8 = qo8 + (size_t)NB * NN * 8;    // NB*NN*8
    unsigned short* vo  = ko8 + (size_t)NB * NN * 8;    // NB*NC*NN (j-permuted)

    proj_mfma_kernel<<<dim3(NN / 64, NB), 256, 0, stream>>>(
        x, wq, bq, wk, bk, wv, bv, qo8, ko8, vo);
    attn_fused_kernel<<<dim3(NN / 32, NB), 256, 0, stream>>>(
        qo8, ko8, vo, x, gamma, out);
}